// Round 3
// baseline (535.414 us; speedup 1.0000x reference)
//
#include <hip/hip_runtime.h>
#include <hip/hip_bf16.h>

#define Bn 2
#define Cn 512
#define Hn 256
#define Wn 256
#define EPSc 1e-5f
#define K345_BLOCKS 128

typedef float f32x4 __attribute__((ext_vector_type(4)));

// ---------------- K1: fused dual depthwise reduction + BN(train) + ReLU + dot ----------------
// block = 512 threads (8 waves), grid = C = 512 blocks; one channel (both batches) each.
// waves 0-3 -> b=0, waves 4-7 -> b=1. wave q handles rows h = q, q+4, ...; lane covers cols 4l..4l+3.
// Writes numv[c*2+b]  (== dot_cb row-major [c][b], == reference reshape order).
// Block 0 also zeroes the spin-barrier counters used by k345 (stream-ordered before it).
__global__ __launch_bounds__(512) void k1_fused(const float* __restrict__ x,
                                                const float* __restrict__ w1,
                                                const float* __restrict__ w2,
                                                const float* __restrict__ g1v,
                                                const float* __restrict__ b1v,
                                                const float* __restrict__ g2v,
                                                const float* __restrict__ b2v,
                                                float* __restrict__ numv,
                                                int* __restrict__ cnt) {
    const int c    = blockIdx.x;
    const int tid  = threadIdx.x;
    const int wv   = tid >> 6;          // 0..7
    const int lane = tid & 63;
    const int bb   = wv >> 2;           // batch 0/1
    const int wq   = wv & 3;            // row phase

    if (c == 0 && tid < 2) cnt[tid] = 0;   // barrier counters for k345

    __shared__ float w1s[Hn];
    __shared__ float s1buf[8][Wn];      // per-wave partial s1 (8 KiB)
    __shared__ float s2s[2][Hn];        // s2[b][h] (2 KiB)
    __shared__ float redbuf[8][4];
    __shared__ float stats[4];          // m1, r1, m2, r2
    __shared__ float dred[8];

    if (tid < Hn) w1s[tid] = w1[c * Hn + tid];
    __syncthreads();

    const float4 w2v = *(const float4*)(w2 + c * Wn + lane * 4);
    const float* __restrict__ xs = x + (size_t)(bb * Cn + c) * (Hn * Wn);

    float4 acc = make_float4(0.f, 0.f, 0.f, 0.f);
    #pragma unroll 2
    for (int h = wq; h < Hn; h += 4) {
        float4 v = *(const float4*)(xs + h * Wn + lane * 4);
        float wh = w1s[h];
        acc.x += v.x * wh; acc.y += v.y * wh;
        acc.z += v.z * wh; acc.w += v.w * wh;
        float p = v.x * w2v.x + v.y * w2v.y + v.z * w2v.z + v.w * w2v.w;
        #pragma unroll
        for (int off = 32; off; off >>= 1) p += __shfl_xor(p, off, 64);
        if (lane == 0) s2s[bb][h] = p;
    }
    ((float4*)(&s1buf[wv][0]))[lane] = acc;
    __syncthreads();

    // thread t -> (bI = t>>8, k = t&255): one s1 value, one s2 value
    const int bI = tid >> 8, k = tid & 255;
    float s1v = s1buf[bI * 4 + 0][k] + s1buf[bI * 4 + 1][k] +
                s1buf[bI * 4 + 2][k] + s1buf[bI * 4 + 3][k];
    float s2v = s2s[bI][k];

    // BN stats over all 512 threads (biased batch stats over (N,H,W))
    float sum1 = s1v, sq1 = s1v * s1v, sum2 = s2v, sq2 = s2v * s2v;
    #pragma unroll
    for (int off = 32; off; off >>= 1) {
        sum1 += __shfl_xor(sum1, off, 64);
        sq1  += __shfl_xor(sq1,  off, 64);
        sum2 += __shfl_xor(sum2, off, 64);
        sq2  += __shfl_xor(sq2,  off, 64);
    }
    if (lane == 0) {
        redbuf[wv][0] = sum1; redbuf[wv][1] = sq1;
        redbuf[wv][2] = sum2; redbuf[wv][3] = sq2;
    }
    __syncthreads();
    if (tid == 0) {
        float t1 = 0.f, t2 = 0.f, t3 = 0.f, t4 = 0.f;
        #pragma unroll
        for (int q = 0; q < 8; q++) {
            t1 += redbuf[q][0]; t2 += redbuf[q][1];
            t3 += redbuf[q][2]; t4 += redbuf[q][3];
        }
        const float inv = 1.0f / 512.0f;
        float m1 = t1 * inv, m2 = t3 * inv;
        stats[0] = m1;
        stats[1] = rsqrtf(t2 * inv - m1 * m1 + EPSc);
        stats[2] = m2;
        stats[3] = rsqrtf(t4 * inv - m2 * m2 + EPSc);
    }
    __syncthreads();

    const float m1 = stats[0], r1 = stats[1], m2 = stats[2], r2 = stats[3];
    const float G1 = g1v[c], B1 = b1v[c], G2 = g2v[c], B2 = b2v[c];

    float a = fmaxf((s1v - m1) * r1 * G1 + B1, 0.f);
    float e = fmaxf((s2v - m2) * r2 * G2 + B2, 0.f);
    float p = a * e;
    #pragma unroll
    for (int off = 32; off; off >>= 1) p += __shfl_xor(p, off, 64);
    if (lane == 0) dred[wv] = p;
    __syncthreads();
    if (tid < 2)
        numv[c * 2 + tid] = dred[tid * 4 + 0] + dred[tid * 4 + 1] +
                            dred[tid * 4 + 2] + dred[tid * 4 + 3];
}

// ---------------- k345: fc1 + fc2 + softmax in one kernel ----------------
// 128 blocks x 256 threads — trivially co-resident on 256 CUs, so device-scope
// spin barriers (counters zeroed by K1) are deadlock-safe.
// phase A: fc1  h1[bb,j] = numv[bb,:]·lw1[j,:] + lb1[j]   (16 outputs/block)
// phase B: fc2  h2[bb,c] = h1[bb,:]·lw2[c,:] + lb2[c]     (8 outputs/block)
// phase C: block 0 softmax over h2 rows -> scl[2*512]
__global__ __launch_bounds__(256) void k345_fc(const float* __restrict__ numv,
                                               const float* __restrict__ lw1,
                                               const float* __restrict__ lb1,
                                               const float* __restrict__ lw2,
                                               const float* __restrict__ lb2,
                                               float* __restrict__ h1,
                                               float* __restrict__ h2,
                                               float* __restrict__ scl,
                                               int* __restrict__ cnt) {
    __shared__ float nv_s[1024];    // numv staged (also reused for h2 in phase C)
    __shared__ float h1_s[2048];
    __shared__ float mxs[2], sms[2];
    const int tid  = threadIdx.x;
    const int wv   = tid >> 6;
    const int lane = tid & 63;

    // ---- phase A: fc1 ----
    #pragma unroll
    for (int j = 0; j < 4; j++) nv_s[tid + 256 * j] = numv[tid + 256 * j];
    __syncthreads();

    #pragma unroll
    for (int q = 0; q < 4; q++) {
        const int out = blockIdx.x * 16 + wv * 4 + q;   // 0..2047
        const int bb = out >> 10, j = out & 1023;
        const float* __restrict__ row = lw1 + (size_t)j * Cn;
        float p = 0.f;
        #pragma unroll
        for (int m = 0; m < 2; m++) {
            float4 a = *(const float4*)(row + lane * 4 + m * 256);
            float4 n = *(const float4*)(&nv_s[bb * 512 + lane * 4 + m * 256]);
            p += a.x * n.x + a.y * n.y + a.z * n.z + a.w * n.w;
        }
        #pragma unroll
        for (int off = 32; off; off >>= 1) p += __shfl_xor(p, off, 64);
        if (lane == 0) h1[bb * 1024 + j] = p + lb1[j];
    }

    // ---- barrier 1: all h1 visible ----
    __threadfence();
    __syncthreads();
    if (tid == 0) {
        atomicAdd(&cnt[0], 1);
        while (atomicAdd(&cnt[0], 0) < K345_BLOCKS) { }
    }
    __syncthreads();
    __threadfence();

    // ---- phase B: fc2 ----
    #pragma unroll
    for (int j = 0; j < 8; j++) h1_s[tid + 256 * j] = h1[tid + 256 * j];
    __syncthreads();

    #pragma unroll
    for (int q = 0; q < 2; q++) {
        const int out = blockIdx.x * 8 + wv * 2 + q;    // 0..1023
        const int bb = out >> 9, c = out & 511;
        const float* __restrict__ row = lw2 + (size_t)c * 1024;
        float p = 0.f;
        #pragma unroll
        for (int m = 0; m < 4; m++) {
            float4 a = *(const float4*)(row + lane * 4 + m * 256);
            float4 n = *(const float4*)(&h1_s[bb * 1024 + lane * 4 + m * 256]);
            p += a.x * n.x + a.y * n.y + a.z * n.z + a.w * n.w;
        }
        #pragma unroll
        for (int off = 32; off; off >>= 1) p += __shfl_xor(p, off, 64);
        if (lane == 0) h2[bb * Cn + c] = p + lb2[c];
    }

    // ---- barrier 2: all h2 visible; only block 0 continues ----
    __threadfence();
    __syncthreads();
    if (tid == 0) atomicAdd(&cnt[1], 1);
    if (blockIdx.x != 0) return;
    if (tid == 0) {
        while (atomicAdd(&cnt[1], 0) < K345_BLOCKS) { }
    }
    __syncthreads();
    __threadfence();

    // ---- phase C: softmax (block 0, waves 0/1 reduce rows 0/1) ----
    #pragma unroll
    for (int j = 0; j < 4; j++) nv_s[tid + 256 * j] = h2[tid + 256 * j];
    __syncthreads();

    if (wv < 2) {
        float mx = -3.402823466e+38f;
        #pragma unroll
        for (int j = 0; j < 8; j++) mx = fmaxf(mx, nv_s[wv * 512 + lane + 64 * j]);
        #pragma unroll
        for (int off = 32; off; off >>= 1) mx = fmaxf(mx, __shfl_xor(mx, off, 64));
        float sm = 0.f;
        #pragma unroll
        for (int j = 0; j < 8; j++) sm += expf(nv_s[wv * 512 + lane + 64 * j] - mx);
        #pragma unroll
        for (int off = 32; off; off >>= 1) sm += __shfl_xor(sm, off, 64);
        if (lane == 0) { mxs[wv] = mx; sms[wv] = sm; }
    }
    __syncthreads();
    #pragma unroll
    for (int j = 0; j < 4; j++) {
        int idx = tid + 256 * j;
        int r = idx >> 9;
        scl[idx] = expf(nv_s[idx] - mxs[r]) / sms[r];
    }
}

// ---------------- K6: out = x * scl[b*512+c]  (linear traversal, NT stores) ----------------
__global__ __launch_bounds__(256) void k6_scale(const float* __restrict__ x,
                                                const float* __restrict__ scl,
                                                float* __restrict__ out, int n4) {
    __shared__ float scls[1024];
    const int t = threadIdx.x;
    #pragma unroll
    for (int j = 0; j < 4; j++) scls[t + 256 * j] = scl[t + 256 * j];
    __syncthreads();

    int i = blockIdx.x * 256 + t;
    const int stride = gridDim.x * 256;
    for (; i < n4; i += stride) {
        f32x4 v = ((const f32x4*)x)[i];
        float s = scls[i >> 14];   // (i*4)/65536 -> slab index b*512+c
        f32x4 r = v * s;
        __builtin_nontemporal_store(r, ((f32x4*)out) + i);
    }
}

extern "C" void kernel_launch(void* const* d_in, const int* in_sizes, int n_in,
                              void* d_out, int out_size, void* d_ws, size_t ws_size,
                              hipStream_t stream) {
    const float* x   = (const float*)d_in[0];
    const float* w1  = (const float*)d_in[1];
    const float* w2  = (const float*)d_in[2];
    const float* g1  = (const float*)d_in[3];
    const float* b1  = (const float*)d_in[4];
    const float* g2  = (const float*)d_in[5];
    const float* b2  = (const float*)d_in[6];
    const float* lw1 = (const float*)d_in[7];
    const float* lb1 = (const float*)d_in[8];
    const float* lw2 = (const float*)d_in[9];
    const float* lb2 = (const float*)d_in[10];
    float* out = (float*)d_out;

    float* ws   = (float*)d_ws;
    float* numv = ws;                       // [1024]
    float* h1   = ws + 1024;                // [2,1024]
    float* h2   = ws + 3072;                // [2,512]
    float* scl  = ws + 4096;                // [2,512]
    int*   cnt  = (int*)(ws + 5120);        // [2] spin-barrier counters (zeroed by K1)

    k1_fused<<<Cn, 512, 0, stream>>>(x, w1, w2, g1, b1, g2, b2, numv, cnt);
    k345_fc<<<K345_BLOCKS, 256, 0, stream>>>(numv, lw1, lb1, lw2, lb2, h1, h2, scl, cnt);

    const int n4 = (Bn * Cn * Hn * Wn) / 4;  // 16,777,216
    k6_scale<<<4096, 256, 0, stream>>>(x, scl, out, n4);
}

// Round 4
// 516.457 us; speedup vs baseline: 1.0367x; 1.0367x over previous
//
#include <hip/hip_runtime.h>
#include <hip/hip_bf16.h>

#define Bn 2
#define Cn 512
#define Hn 256
#define Wn 256
#define EPSc 1e-5f

typedef float f32x4 __attribute__((ext_vector_type(4)));

// ---------------- K1: fused dual depthwise reduction + BN(train) + ReLU + dot ----------------
// block = 512 threads (8 waves), grid = C = 512 blocks; one channel (both batches) each.
// waves 0-3 -> b=0, waves 4-7 -> b=1. wave q handles rows h = q, q+4, ...; lane covers cols 4l..4l+3.
// After streaming x, BN stats (over b,k = 512 vals) + ReLU + per-(c,b) dot computed in-block.
// Writes only numv[c*2+b]  (== dot_cb row-major [c][b], == reference reshape order).
// x reads are normal (cache-allocating) on purpose — K6 re-reads x from L3.
__global__ __launch_bounds__(512) void k1_fused(const float* __restrict__ x,
                                                const float* __restrict__ w1,
                                                const float* __restrict__ w2,
                                                const float* __restrict__ g1v,
                                                const float* __restrict__ b1v,
                                                const float* __restrict__ g2v,
                                                const float* __restrict__ b2v,
                                                float* __restrict__ numv) {
    const int c    = blockIdx.x;
    const int tid  = threadIdx.x;
    const int wv   = tid >> 6;          // 0..7
    const int lane = tid & 63;
    const int bb   = wv >> 2;           // batch 0/1
    const int wq   = wv & 3;            // row phase

    __shared__ float w1s[Hn];
    __shared__ float s1buf[8][Wn];      // per-wave partial s1 (8 KiB)
    __shared__ float s2s[2][Hn];        // s2[b][h] (2 KiB)
    __shared__ float redbuf[8][4];
    __shared__ float stats[4];          // m1, r1, m2, r2
    __shared__ float dred[8];

    if (tid < Hn) w1s[tid] = w1[c * Hn + tid];
    __syncthreads();

    const float4 w2v = *(const float4*)(w2 + c * Wn + lane * 4);
    const float* __restrict__ xs = x + (size_t)(bb * Cn + c) * (Hn * Wn);

    float4 acc = make_float4(0.f, 0.f, 0.f, 0.f);
    #pragma unroll 2
    for (int h = wq; h < Hn; h += 4) {
        float4 v = *(const float4*)(xs + h * Wn + lane * 4);
        float wh = w1s[h];
        acc.x += v.x * wh; acc.y += v.y * wh;
        acc.z += v.z * wh; acc.w += v.w * wh;
        float p = v.x * w2v.x + v.y * w2v.y + v.z * w2v.z + v.w * w2v.w;
        #pragma unroll
        for (int off = 32; off; off >>= 1) p += __shfl_xor(p, off, 64);
        if (lane == 0) s2s[bb][h] = p;
    }
    ((float4*)(&s1buf[wv][0]))[lane] = acc;
    __syncthreads();

    // thread t -> (bI = t>>8, k = t&255): one s1 value, one s2 value
    const int bI = tid >> 8, k = tid & 255;
    float s1v = s1buf[bI * 4 + 0][k] + s1buf[bI * 4 + 1][k] +
                s1buf[bI * 4 + 2][k] + s1buf[bI * 4 + 3][k];
    float s2v = s2s[bI][k];

    // BN stats over all 512 threads (biased batch stats over (N,H,W))
    float sum1 = s1v, sq1 = s1v * s1v, sum2 = s2v, sq2 = s2v * s2v;
    #pragma unroll
    for (int off = 32; off; off >>= 1) {
        sum1 += __shfl_xor(sum1, off, 64);
        sq1  += __shfl_xor(sq1,  off, 64);
        sum2 += __shfl_xor(sum2, off, 64);
        sq2  += __shfl_xor(sq2,  off, 64);
    }
    if (lane == 0) {
        redbuf[wv][0] = sum1; redbuf[wv][1] = sq1;
        redbuf[wv][2] = sum2; redbuf[wv][3] = sq2;
    }
    __syncthreads();
    if (tid == 0) {
        float t1 = 0.f, t2 = 0.f, t3 = 0.f, t4 = 0.f;
        #pragma unroll
        for (int q = 0; q < 8; q++) {
            t1 += redbuf[q][0]; t2 += redbuf[q][1];
            t3 += redbuf[q][2]; t4 += redbuf[q][3];
        }
        const float inv = 1.0f / 512.0f;
        float m1 = t1 * inv, m2 = t3 * inv;
        stats[0] = m1;
        stats[1] = rsqrtf(t2 * inv - m1 * m1 + EPSc);
        stats[2] = m2;
        stats[3] = rsqrtf(t4 * inv - m2 * m2 + EPSc);
    }
    __syncthreads();

    const float m1 = stats[0], r1 = stats[1], m2 = stats[2], r2 = stats[3];
    const float G1 = g1v[c], B1 = b1v[c], G2 = g2v[c], B2 = b2v[c];

    float a = fmaxf((s1v - m1) * r1 * G1 + B1, 0.f);
    float e = fmaxf((s2v - m2) * r2 * G2 + B2, 0.f);
    float p = a * e;
    #pragma unroll
    for (int off = 32; off; off >>= 1) p += __shfl_xor(p, off, 64);
    if (lane == 0) dred[wv] = p;
    __syncthreads();
    if (tid < 2)
        numv[c * 2 + tid] = dred[tid * 4 + 0] + dred[tid * 4 + 1] +
                            dred[tid * 4 + 2] + dred[tid * 4 + 3];
}

// ---------------- K3: fc1  h1[bb,j] = numv[bb,:]·lw1[j,:] + lb1[j] ----------------
__global__ __launch_bounds__(256) void k3_fc1(const float* __restrict__ numv,
                                              const float* __restrict__ lw1,
                                              const float* __restrict__ lb1,
                                              float* __restrict__ h1) {
    const int wid  = blockIdx.x * 4 + (threadIdx.x >> 6);  // 0..2047
    const int lane = threadIdx.x & 63;
    const int bb = wid >> 10, j = wid & 1023;
    const float* __restrict__ row = lw1 + (size_t)j * Cn;
    const float* __restrict__ nv  = numv + bb * Cn;
    float p = 0.f;
    #pragma unroll
    for (int m = 0; m < 2; m++) {
        float4 a = *(const float4*)(row + lane * 4 + m * 256);
        float4 n = *(const float4*)(nv  + lane * 4 + m * 256);
        p += a.x * n.x + a.y * n.y + a.z * n.z + a.w * n.w;
    }
    #pragma unroll
    for (int off = 32; off; off >>= 1) p += __shfl_xor(p, off, 64);
    if (lane == 0) h1[bb * 1024 + j] = p + lb1[j];
}

// ---------------- K4: fc2  h2[bb,c] = h1[bb,:]·lw2[c,:] + lb2[c] ----------------
__global__ __launch_bounds__(256) void k4_fc2(const float* __restrict__ h1,
                                              const float* __restrict__ lw2,
                                              const float* __restrict__ lb2,
                                              float* __restrict__ h2) {
    const int wid  = blockIdx.x * 4 + (threadIdx.x >> 6);  // 0..1023
    const int lane = threadIdx.x & 63;
    const int bb = wid >> 9, c = wid & 511;
    const float* __restrict__ row = lw2 + (size_t)c * 1024;
    const float* __restrict__ hv  = h1 + bb * 1024;
    float p = 0.f;
    #pragma unroll
    for (int m = 0; m < 4; m++) {
        float4 a = *(const float4*)(row + lane * 4 + m * 256);
        float4 n = *(const float4*)(hv  + lane * 4 + m * 256);
        p += a.x * n.x + a.y * n.y + a.z * n.z + a.w * n.w;
    }
    #pragma unroll
    for (int off = 32; off; off >>= 1) p += __shfl_xor(p, off, 64);
    if (lane == 0) h2[bb * Cn + c] = p + lb2[c];
}

// ---------------- K6: per-block softmax (redundant, 4 KB L2-hit) + out = x * scale ----------------
// Linear traversal (R2 showed order games are a null). NT stores keep the 268 MB write
// stream from evicting the L3-resident x that K1 just streamed.
__global__ __launch_bounds__(256) void k6_softmax_scale(const float* __restrict__ x,
                                                        const float* __restrict__ h2,
                                                        float* __restrict__ out, int n4) {
    __shared__ float h2s[1024];
    __shared__ float scls[1024];
    __shared__ float mxs[2], sms[2];
    const int t = threadIdx.x;

    #pragma unroll
    for (int j = 0; j < 4; j++) h2s[t + 256 * j] = h2[t + 256 * j];
    __syncthreads();

    const int wv = t >> 6, lane = t & 63;
    if (wv < 2) {  // wave 0 -> row 0 (b=0), wave 1 -> row 1 (b=1)
        float mx = -3.402823466e+38f;
        #pragma unroll
        for (int j = 0; j < 8; j++) mx = fmaxf(mx, h2s[wv * 512 + lane + 64 * j]);
        #pragma unroll
        for (int off = 32; off; off >>= 1) mx = fmaxf(mx, __shfl_xor(mx, off, 64));
        float sm = 0.f;
        #pragma unroll
        for (int j = 0; j < 8; j++) sm += expf(h2s[wv * 512 + lane + 64 * j] - mx);
        #pragma unroll
        for (int off = 32; off; off >>= 1) sm += __shfl_xor(sm, off, 64);
        if (lane == 0) { mxs[wv] = mx; sms[wv] = sm; }
    }
    __syncthreads();
    #pragma unroll
    for (int j = 0; j < 4; j++) {
        int idx = t + 256 * j;
        int r = idx >> 9;
        scls[idx] = expf(h2s[idx] - mxs[r]) / sms[r];
    }
    __syncthreads();

    int i = blockIdx.x * 256 + t;
    const int stride = gridDim.x * 256;
    for (; i < n4; i += stride) {
        f32x4 v = ((const f32x4*)x)[i];
        float s = scls[i >> 14];   // (i*4)/65536 -> slab index b*512+c
        f32x4 r = v * s;
        __builtin_nontemporal_store(r, ((f32x4*)out) + i);
    }
}

extern "C" void kernel_launch(void* const* d_in, const int* in_sizes, int n_in,
                              void* d_out, int out_size, void* d_ws, size_t ws_size,
                              hipStream_t stream) {
    const float* x   = (const float*)d_in[0];
    const float* w1  = (const float*)d_in[1];
    const float* w2  = (const float*)d_in[2];
    const float* g1  = (const float*)d_in[3];
    const float* b1  = (const float*)d_in[4];
    const float* b2g = (const float*)d_in[5];
    const float* b2  = (const float*)d_in[6];
    const float* lw1 = (const float*)d_in[7];
    const float* lb1 = (const float*)d_in[8];
    const float* lw2 = (const float*)d_in[9];
    const float* lb2 = (const float*)d_in[10];
    float* out = (float*)d_out;

    float* ws   = (float*)d_ws;
    float* numv = ws;                       // [1024]
    float* h1   = ws + 1024;                // [2,1024]
    float* h2   = ws + 3072;                // [2,512]

    k1_fused<<<Cn, 512, 0, stream>>>(x, w1, w2, g1, b1, b2g, b2, numv);
    k3_fc1<<<512, 256, 0, stream>>>(numv, lw1, lb1, h1);
    k4_fc2<<<256, 256, 0, stream>>>(h1, lw2, lb2, h2);

    const int n4 = (Bn * Cn * Hn * Wn) / 4;  // 16,777,216
    k6_softmax_scale<<<2048, 256, 0, stream>>>(x, h2, out, n4);
}

// Round 5
// 508.863 us; speedup vs baseline: 1.0522x; 1.0149x over previous
//
#include <hip/hip_runtime.h>
#include <hip/hip_bf16.h>

#define Bn 2
#define Cn 512
#define Hn 256
#define Wn 256
#define EPSc 1e-5f

typedef float f32x4 __attribute__((ext_vector_type(4)));

// ---------------- K1: fused dual depthwise reduction + BN(train) + ReLU + dot ----------------
// block = 512 threads (8 waves), grid = C = 512 blocks; one channel (both batches) each.
// waves 0-3 -> b=0, waves 4-7 -> b=1. wave q handles rows h = q, q+4, ...; lane covers cols 4l..4l+3.
// After streaming x, BN stats (over b,k = 512 vals) + ReLU + per-(c,b) dot computed in-block.
// Writes only numv[c*2+b]  (== dot_cb row-major [c][b], == reference reshape order).
// x reads are normal (cache-allocating) on purpose — K6 re-reads x from L3.
__global__ __launch_bounds__(512) void k1_fused(const float* __restrict__ x,
                                                const float* __restrict__ w1,
                                                const float* __restrict__ w2,
                                                const float* __restrict__ g1v,
                                                const float* __restrict__ b1v,
                                                const float* __restrict__ g2v,
                                                const float* __restrict__ b2v,
                                                float* __restrict__ numv) {
    const int c    = blockIdx.x;
    const int tid  = threadIdx.x;
    const int wv   = tid >> 6;          // 0..7
    const int lane = tid & 63;
    const int bb   = wv >> 2;           // batch 0/1
    const int wq   = wv & 3;            // row phase

    __shared__ float w1s[Hn];
    __shared__ float s1buf[8][Wn];      // per-wave partial s1 (8 KiB)
    __shared__ float s2s[2][Hn];        // s2[b][h] (2 KiB)
    __shared__ float redbuf[8][4];
    __shared__ float stats[4];          // m1, r1, m2, r2
    __shared__ float dred[8];

    if (tid < Hn) w1s[tid] = w1[c * Hn + tid];
    __syncthreads();

    const float4 w2v = *(const float4*)(w2 + c * Wn + lane * 4);
    const float* __restrict__ xs = x + (size_t)(bb * Cn + c) * (Hn * Wn);

    float4 acc = make_float4(0.f, 0.f, 0.f, 0.f);
    #pragma unroll 2
    for (int h = wq; h < Hn; h += 4) {
        float4 v = *(const float4*)(xs + h * Wn + lane * 4);
        float wh = w1s[h];
        acc.x += v.x * wh; acc.y += v.y * wh;
        acc.z += v.z * wh; acc.w += v.w * wh;
        float p = v.x * w2v.x + v.y * w2v.y + v.z * w2v.z + v.w * w2v.w;
        #pragma unroll
        for (int off = 32; off; off >>= 1) p += __shfl_xor(p, off, 64);
        if (lane == 0) s2s[bb][h] = p;
    }
    ((float4*)(&s1buf[wv][0]))[lane] = acc;
    __syncthreads();

    // thread t -> (bI = t>>8, k = t&255): one s1 value, one s2 value
    const int bI = tid >> 8, k = tid & 255;
    float s1v = s1buf[bI * 4 + 0][k] + s1buf[bI * 4 + 1][k] +
                s1buf[bI * 4 + 2][k] + s1buf[bI * 4 + 3][k];
    float s2v = s2s[bI][k];

    // BN stats over all 512 threads (biased batch stats over (N,H,W))
    float sum1 = s1v, sq1 = s1v * s1v, sum2 = s2v, sq2 = s2v * s2v;
    #pragma unroll
    for (int off = 32; off; off >>= 1) {
        sum1 += __shfl_xor(sum1, off, 64);
        sq1  += __shfl_xor(sq1,  off, 64);
        sum2 += __shfl_xor(sum2, off, 64);
        sq2  += __shfl_xor(sq2,  off, 64);
    }
    if (lane == 0) {
        redbuf[wv][0] = sum1; redbuf[wv][1] = sq1;
        redbuf[wv][2] = sum2; redbuf[wv][3] = sq2;
    }
    __syncthreads();
    if (tid == 0) {
        float t1 = 0.f, t2 = 0.f, t3 = 0.f, t4 = 0.f;
        #pragma unroll
        for (int q = 0; q < 8; q++) {
            t1 += redbuf[q][0]; t2 += redbuf[q][1];
            t3 += redbuf[q][2]; t4 += redbuf[q][3];
        }
        const float inv = 1.0f / 512.0f;
        float m1 = t1 * inv, m2 = t3 * inv;
        stats[0] = m1;
        stats[1] = rsqrtf(t2 * inv - m1 * m1 + EPSc);
        stats[2] = m2;
        stats[3] = rsqrtf(t4 * inv - m2 * m2 + EPSc);
    }
    __syncthreads();

    const float m1 = stats[0], r1 = stats[1], m2 = stats[2], r2 = stats[3];
    const float G1 = g1v[c], B1 = b1v[c], G2 = g2v[c], B2 = b2v[c];

    float a = fmaxf((s1v - m1) * r1 * G1 + B1, 0.f);
    float e = fmaxf((s2v - m2) * r2 * G2 + B2, 0.f);
    float p = a * e;
    #pragma unroll
    for (int off = 32; off; off >>= 1) p += __shfl_xor(p, off, 64);
    if (lane == 0) dred[wv] = p;
    __syncthreads();
    if (tid < 2)
        numv[c * 2 + tid] = dred[tid * 4 + 0] + dred[tid * 4 + 1] +
                            dred[tid * 4 + 2] + dred[tid * 4 + 3];
}

// ---------------- K3: fc1  h1[bb,j] = numv[bb,:]·lw1[j,:] + lb1[j] ----------------
__global__ __launch_bounds__(256) void k3_fc1(const float* __restrict__ numv,
                                              const float* __restrict__ lw1,
                                              const float* __restrict__ lb1,
                                              float* __restrict__ h1) {
    const int wid  = blockIdx.x * 4 + (threadIdx.x >> 6);  // 0..2047
    const int lane = threadIdx.x & 63;
    const int bb = wid >> 10, j = wid & 1023;
    const float* __restrict__ row = lw1 + (size_t)j * Cn;
    const float* __restrict__ nv  = numv + bb * Cn;
    float p = 0.f;
    #pragma unroll
    for (int m = 0; m < 2; m++) {
        float4 a = *(const float4*)(row + lane * 4 + m * 256);
        float4 n = *(const float4*)(nv  + lane * 4 + m * 256);
        p += a.x * n.x + a.y * n.y + a.z * n.z + a.w * n.w;
    }
    #pragma unroll
    for (int off = 32; off; off >>= 1) p += __shfl_xor(p, off, 64);
    if (lane == 0) h1[bb * 1024 + j] = p + lb1[j];
}

// ---------------- K4: fc2  h2[bb,c] = h1[bb,:]·lw2[c,:] + lb2[c] ----------------
__global__ __launch_bounds__(256) void k4_fc2(const float* __restrict__ h1,
                                              const float* __restrict__ lw2,
                                              const float* __restrict__ lb2,
                                              float* __restrict__ h2) {
    const int wid  = blockIdx.x * 4 + (threadIdx.x >> 6);  // 0..1023
    const int lane = threadIdx.x & 63;
    const int bb = wid >> 9, c = wid & 511;
    const float* __restrict__ row = lw2 + (size_t)c * 1024;
    const float* __restrict__ hv  = h1 + bb * 1024;
    float p = 0.f;
    #pragma unroll
    for (int m = 0; m < 4; m++) {
        float4 a = *(const float4*)(row + lane * 4 + m * 256);
        float4 n = *(const float4*)(hv  + lane * 4 + m * 256);
        p += a.x * n.x + a.y * n.y + a.z * n.z + a.w * n.w;
    }
    #pragma unroll
    for (int off = 32; off; off >>= 1) p += __shfl_xor(p, off, 64);
    if (lane == 0) h2[bb * Cn + c] = p + lb2[c];
}

// ---------------- K6: per-block softmax (redundant, 4 KB L2-hit) + out = x * scale ----------------
// Linear traversal; grid 4096 (2048 measured +7.5 µs in R4). NT stores keep the 268 MB write
// stream from evicting the L3-resident x that K1 just streamed.
__global__ __launch_bounds__(256) void k6_softmax_scale(const float* __restrict__ x,
                                                        const float* __restrict__ h2,
                                                        float* __restrict__ out, int n4) {
    __shared__ float h2s[1024];
    __shared__ float scls[1024];
    __shared__ float mxs[2], sms[2];
    const int t = threadIdx.x;

    #pragma unroll
    for (int j = 0; j < 4; j++) h2s[t + 256 * j] = h2[t + 256 * j];
    __syncthreads();

    const int wv = t >> 6, lane = t & 63;
    if (wv < 2) {  // wave 0 -> row 0 (b=0), wave 1 -> row 1 (b=1)
        float mx = -3.402823466e+38f;
        #pragma unroll
        for (int j = 0; j < 8; j++) mx = fmaxf(mx, h2s[wv * 512 + lane + 64 * j]);
        #pragma unroll
        for (int off = 32; off; off >>= 1) mx = fmaxf(mx, __shfl_xor(mx, off, 64));
        float sm = 0.f;
        #pragma unroll
        for (int j = 0; j < 8; j++) sm += expf(h2s[wv * 512 + lane + 64 * j] - mx);
        #pragma unroll
        for (int off = 32; off; off >>= 1) sm += __shfl_xor(sm, off, 64);
        if (lane == 0) { mxs[wv] = mx; sms[wv] = sm; }
    }
    __syncthreads();
    #pragma unroll
    for (int j = 0; j < 4; j++) {
        int idx = t + 256 * j;
        int r = idx >> 9;
        scls[idx] = expf(h2s[idx] - mxs[r]) / sms[r];
    }
    __syncthreads();

    int i = blockIdx.x * 256 + t;
    const int stride = gridDim.x * 256;
    for (; i < n4; i += stride) {
        f32x4 v = ((const f32x4*)x)[i];
        float s = scls[i >> 14];   // (i*4)/65536 -> slab index b*512+c
        f32x4 r = v * s;
        __builtin_nontemporal_store(r, ((f32x4*)out) + i);
    }
}

extern "C" void kernel_launch(void* const* d_in, const int* in_sizes, int n_in,
                              void* d_out, int out_size, void* d_ws, size_t ws_size,
                              hipStream_t stream) {
    const float* x   = (const float*)d_in[0];
    const float* w1  = (const float*)d_in[1];
    const float* w2  = (const float*)d_in[2];
    const float* g1  = (const float*)d_in[3];
    const float* b1  = (const float*)d_in[4];
    const float* g2  = (const float*)d_in[5];
    const float* b2  = (const float*)d_in[6];
    const float* lw1 = (const float*)d_in[7];
    const float* lb1 = (const float*)d_in[8];
    const float* lw2 = (const float*)d_in[9];
    const float* lb2 = (const float*)d_in[10];
    float* out = (float*)d_out;

    float* ws   = (float*)d_ws;
    float* numv = ws;                       // [1024]
    float* h1   = ws + 1024;                // [2,1024]
    float* h2   = ws + 3072;                // [2,512]

    k1_fused<<<Cn, 512, 0, stream>>>(x, w1, w2, g1, b1, g2, b2, numv);
    k3_fc1<<<512, 256, 0, stream>>>(numv, lw1, lb1, h1);
    k4_fc2<<<256, 256, 0, stream>>>(h1, lw2, lb2, h2);

    const int n4 = (Bn * Cn * Hn * Wn) / 4;  // 16,777,216
    k6_softmax_scale<<<4096, 256, 0, stream>>>(x, h2, out, n4);
}